// Round 1
// baseline (204.024 us; speedup 1.0000x reference)
//
#include <hip/hip_runtime.h>

#define NCOL 10752   // 512*21
#define NG 15
#define NTILES 37

typedef __bf16 bf16;
typedef __attribute__((ext_vector_type(8))) __bf16 bf16x8;
typedef __attribute__((ext_vector_type(4))) __bf16 bf16x4;
typedef __attribute__((ext_vector_type(2))) __bf16 bf16x2;
typedef __attribute__((ext_vector_type(4))) float f32x4;

__constant__ int c_gsize[NG]  = {64,128,256,96,160,224,192,288,320,112,80,48,32,16,32};
__constant__ int c_gstart[NG] = {0,64,192,448,544,704,928,1120,1408,1728,1840,1920,1968,2000,2016};
// 64-row tiles, largest groups first (long-running blocks dispatched first),
// same-group tile-rows adjacent in y so their shared X stripe stays L3-hot.
__constant__ int c_tgrp[NTILES] = {8,8,8,8,8, 7,7,7,7,7, 2,2,2,2, 5,5,5,5, 6,6,6, 4,4,4, 1,1, 9,9, 3,3, 10,10, 0, 11, 12, 13, 14};
__constant__ int c_trow[NTILES] = {0,64,128,192,256, 0,64,128,192,256, 0,64,128,192, 0,64,128,192, 0,64,128, 0,64,128, 0,64, 0,64, 0,64, 0,64, 0, 0, 0, 0, 0};

struct MatPtrs { const float* p[NG]; };

constexpr int BM = 64, BN = 64, BK = 32, BKp = 40;

// LDS swizzles: XOR multiples of 8 k-elements (16B) so ds_read_b128 stays contiguous.
// B write lanes are col-stride-4 at 80B rows -> key must mix lc bits 2..5 to avoid
// the 8-way pattern; ((lc>>2)^(lc>>4))&3 gives exact 2-way (free) on writes.
__device__ __forceinline__ int swzB(int lc, int k) {
    return k ^ ((((lc >> 2) ^ (lc >> 4)) & 3) << 3);
}
__device__ __forceinline__ int swzA(int r, int k) {
    return k ^ (((r >> 1) & 3) << 3);
}

__global__ __launch_bounds__(256, 6)   // cap ~85 unified regs -> 6 blocks/CU (LDS allows 8)
void matapply_kernel(const float* __restrict__ x, MatPtrs mats, float* __restrict__ out)
{
    // double-buffered: 2 * (64*40 + 64*40) * 2B = 20480 B
    __shared__ __align__(16) bf16 sA[2][BM][BKp];   // M tile: [row][k]
    __shared__ __align__(16) bf16 sB[2][BN][BKp];   // X tile transposed: [col][k]

    const int tid    = threadIdx.x;
    const int colb   = blockIdx.x * BN;      // fastest dim: adjacent blocks = adjacent cols
    const int tileid = blockIdx.y;

    const int grp  = c_tgrp[tileid];
    const int row0 = c_trow[tileid];
    const int g    = c_gsize[grp];
    const int s    = c_gstart[grp];
    const float* __restrict__ M = mats.p[grp];

    const int wave = tid >> 6;
    const int lane = tid & 63;
    const int wr   = (wave & 1) * 32;        // 2x2 wave grid, 32x32 per wave
    const int wc   = (wave >> 1) * 32;
    const int lm   = lane & 15;
    const int kq   = lane >> 4;
    const int kb   = kq * 8;

    // staging assignments
    const int aK = (tid & 7) * 4;            // A: k offset (float4 along k)
    const int aR = tid >> 3;                 // A: row base (0..31), rows aR, aR+32
    const int bC = (tid & 15) * 4;           // B: col offset (float4 along cols)
    const int bK = (tid >> 4) * 2;           // B: k row base (2 rows)

    const int nIter = (g + BK - 1) / BK;

    f32x4 acc[2][2];
    #pragma unroll
    for (int i = 0; i < 2; i++)
        #pragma unroll
        for (int j = 0; j < 2; j++)
            acc[i][j] = (f32x4){0.f, 0.f, 0.f, 0.f};

    float4 av[2], xv[2];

    // ---- prologue: load iter 0 into regs ----
    #pragma unroll
    for (int i = 0; i < 2; i++) {
        int r = aR + 32 * i;
        av[i] = make_float4(0.f, 0.f, 0.f, 0.f);
        if ((row0 + r) < g && aK < g)
            av[i] = *(const float4*)(M + (size_t)(row0 + r) * g + aK);
    }
    #pragma unroll
    for (int j = 0; j < 2; j++)
        xv[j] = *(const float4*)(x + (size_t)(s + bK + j) * NCOL + colb + bC);

    // store iter 0 into buf 0
    #pragma unroll
    for (int i = 0; i < 2; i++) {
        int r = aR + 32 * i;
        bf16x4 w;
        w[0] = (bf16)av[i].x; w[1] = (bf16)av[i].y; w[2] = (bf16)av[i].z; w[3] = (bf16)av[i].w;
        *(bf16x4*)&sA[0][r][swzA(r, aK)] = w;
    }
    #pragma unroll
    for (int cc = 0; cc < 4; cc++) {
        int lc = bC + cc;
        bf16x2 w;
        w[0] = (bf16)(((const float*)&xv[0])[cc]);
        w[1] = (bf16)(((const float*)&xv[1])[cc]);
        *(bf16x2*)&sB[0][lc][swzB(lc, bK)] = w;
    }
    __syncthreads();

    for (int it = 0; it < nIter; ++it) {
        const int cur = it & 1;
        const bool more = (it + 1) < nIter;

        // ---- issue global loads for next iter (in flight during compute) ----
        if (more) {
            const int k0 = (it + 1) * BK;
            #pragma unroll
            for (int i = 0; i < 2; i++) {
                int r = aR + 32 * i;
                av[i] = make_float4(0.f, 0.f, 0.f, 0.f);
                if ((row0 + r) < g && (k0 + aK) < g)
                    av[i] = *(const float4*)(M + (size_t)(row0 + r) * g + k0 + aK);
            }
            #pragma unroll
            for (int j = 0; j < 2; j++)
                xv[j] = *(const float4*)(x + (size_t)(s + k0 + bK + j) * NCOL + colb + bC);
        }

        // ---- compute from buf[cur] ----
        bf16x8 af[2], bfr[2];
        #pragma unroll
        for (int i = 0; i < 2; i++) {
            int r = wr + 16 * i + lm;
            af[i] = *(const bf16x8*)&sA[cur][r][swzA(r, kb)];
        }
        #pragma unroll
        for (int j = 0; j < 2; j++) {
            int lc = wc + 16 * j + lm;
            bfr[j] = *(const bf16x8*)&sB[cur][lc][swzB(lc, kb)];
        }
        #pragma unroll
        for (int i = 0; i < 2; i++)
            #pragma unroll
            for (int j = 0; j < 2; j++)
                acc[i][j] = __builtin_amdgcn_mfma_f32_16x16x32_bf16(af[i], bfr[j], acc[i][j], 0, 0, 0);

        // ---- drain loads, stage next tile into buf[1-cur], one barrier ----
        if (more) {
            const int nxt = 1 - cur;
            #pragma unroll
            for (int i = 0; i < 2; i++) {
                int r = aR + 32 * i;
                bf16x4 w;
                w[0] = (bf16)av[i].x; w[1] = (bf16)av[i].y; w[2] = (bf16)av[i].z; w[3] = (bf16)av[i].w;
                *(bf16x4*)&sA[nxt][r][swzA(r, aK)] = w;
            }
            #pragma unroll
            for (int cc = 0; cc < 4; cc++) {
                int lc = bC + cc;
                bf16x2 w;
                w[0] = (bf16)(((const float*)&xv[0])[cc]);
                w[1] = (bf16)(((const float*)&xv[1])[cc]);
                *(bf16x2*)&sB[nxt][lc][swzB(lc, bK)] = w;
            }
            __syncthreads();
        }
    }

    // ---- epilogue: C/D layout col=lane&15, row=(lane>>4)*4+reg ----
    #pragma unroll
    for (int i = 0; i < 2; i++) {
        #pragma unroll
        for (int r = 0; r < 4; r++) {
            int row = row0 + wr + 16 * i + kq * 4 + r;
            if (row < g) {
                float* orow = out + (size_t)(s + row) * NCOL + colb + wc;
                orow[lm]      = acc[i][0][r];
                orow[16 + lm] = acc[i][1][r];
            }
        }
    }
}

extern "C" void kernel_launch(void* const* d_in, const int* in_sizes, int n_in,
                              void* d_out, int out_size, void* d_ws, size_t ws_size,
                              hipStream_t stream)
{
    const float* x = (const float*)d_in[0];
    MatPtrs mp;
    for (int i = 0; i < NG; i++) mp.p[i] = (const float*)d_in[1 + i];
    float* out = (float*)d_out;

    dim3 grid(NCOL / BN, NTILES);   // (168, 37): colb fastest for DRAM page coalescing
    dim3 block(256);
    matapply_kernel<<<grid, block, 0, stream>>>(x, mp, out);
}

// Round 2
// 192.784 us; speedup vs baseline: 1.0583x; 1.0583x over previous
//
#include <hip/hip_runtime.h>

#define NCOL 10752   // 512*21
#define NG 15
#define NTILES 23
#define WS_NEED 1064960   // 130 k-chunks * 8192 B of A images

typedef __bf16 bf16;
typedef __attribute__((ext_vector_type(8))) __bf16 bf16x8;
typedef __attribute__((ext_vector_type(4))) __bf16 bf16x4;
typedef __attribute__((ext_vector_type(4))) float f32x4;

__constant__ int c_gsize[NG]  = {64,128,256,96,160,224,192,288,320,112,80,48,32,16,32};
__constant__ int c_gstart[NG] = {0,64,192,448,544,704,928,1120,1408,1728,1840,1920,1968,2000,2016};
// tiles sorted by descending group size (long blocks dispatched first)
__constant__ int c_tgrp[NTILES]  = {8,8,8,7,7,7,2,2,5,5,6,6,4,4,1,9,3,10,0,11,12,14,13};
__constant__ int c_trow[NTILES]  = {0,128,256,0,128,256,0,128,0,128,0,128,0,128,0,0,0,0,0,0,0,0,0};
__constant__ int c_niter[NTILES] = {10,10,10,9,9,9,8,8,7,7,6,6,5,5,4,4,3,3,2,2,1,1,1};
// prefix sum of c_niter: A-image base offset per tile, in units of 4096 bf16 (8 KB)
__constant__ int c_tbase[NTILES] = {0,10,20,30,39,48,57,65,73,80,87,93,99,104,109,113,117,120,123,125,127,128,129};

struct MatPtrs { const float* p[NG]; };

constexpr int BM = 128, BN = 128, BK = 32, BKp = 40;

// ---------------------------------------------------------------------------
// Pre-pass: convert group matrices into fragment-major bf16 tile images.
// Image unit u (0..511) of k-chunk kt of tile t holds A[row0 + (u>>6)*16 + (u&15)]
// [kt*32 + ((u>>4)&3)*8 .. +7], zero-padded outside the group. This is EXACTLY
// the LDS image global_load_lds produces (lane*16B) and the MFMA A-frag order.
// ---------------------------------------------------------------------------
__global__ __launch_bounds__(256)
void prep_kernel(MatPtrs mats, bf16* __restrict__ ws)
{
    const int kt = blockIdx.x, tile = blockIdx.y;
    if (kt >= c_niter[tile]) return;
    const int grp  = c_tgrp[tile];
    const int row0 = c_trow[tile];
    const int g    = c_gsize[grp];
    const float* __restrict__ M = mats.p[grp];
    bf16* dst = ws + (size_t)(c_tbase[tile] + kt) * 4096;

    #pragma unroll
    for (int h = 0; h < 2; h++) {
        const int u    = threadIdx.x + h * 256;
        const int l    = u & 63;
        const int st   = u >> 6;
        const int row  = row0 + st * 16 + (l & 15);
        const int kcol = kt * 32 + (l >> 4) * 8;
        bf16x8 w = {};
        if (row < g && kcol < g) {          // g % 16 == 0 -> octet fully in/out
            const float* src = M + (size_t)row * g + kcol;
            #pragma unroll
            for (int j = 0; j < 8; j++) w[j] = (bf16)src[j];
        }
        *(bf16x8*)(dst + (size_t)u * 8) = w;
    }
}

// ---------------------------------------------------------------------------
// Main GEMM: A staged via global_load_lds from pre-tiled images (no regs, no
// cvt, no bounds checks, conflict-free), B staged via regs as before.
// regs: ~56 arch + 64 acc <= 128 -> 16 waves/CU; LDS 36.9 KB -> 4 blocks/CU.
// ---------------------------------------------------------------------------
__global__ __launch_bounds__(256, 4)
void matapply_kernel(const float* __restrict__ x, const bf16* __restrict__ aws,
                     float* __restrict__ out)
{
    __shared__ bf16 sA[2][4096];        // fragment-major: [subtile 0..7][lane][8]
    __shared__ bf16 sB[2][BN][BKp];     // X tile transposed: [col][k], k XOR-swizzled

    const int tid    = threadIdx.x;
    const int colb   = blockIdx.x * BN;
    const int tileid = blockIdx.y;

    const int grp  = c_tgrp[tileid];
    const int g    = c_gsize[grp];
    const int s    = c_gstart[grp];
    const int row0 = c_trow[tileid];
    const bf16* __restrict__ aimg = aws + (size_t)c_tbase[tileid] * 4096;

    const int wave = tid >> 6;
    const int lane = tid & 63;
    const int wr   = (wave & 1) * 64;
    const int wc   = (wave >> 1) * 64;
    const int lm   = lane & 15;
    const int kq   = lane >> 4;
    const int kb   = kq * 8;

    // B staging assignment (identical to round-0 kernel)
    const int bC = (tid & 31) * 4;
    const int bK = (tid >> 5) * 4;

    const int nIter = (g + BK - 1) / BK;

    f32x4 acc[4][4];
    #pragma unroll
    for (int i = 0; i < 4; i++)
        #pragma unroll
        for (int j = 0; j < 4; j++)
            acc[i][j] = (f32x4){0.f, 0.f, 0.f, 0.f};

    float4 xv[4];

    // A: two 1KB global_load_lds per wave fill subtiles 2w, 2w+1
    auto glds_a = [&](int buf, int kt) {
        const bf16* src = aimg + (size_t)kt * 4096 + (size_t)(wave * 2) * 512 + lane * 8;
        #pragma unroll
        for (int c = 0; c < 2; c++)
            __builtin_amdgcn_global_load_lds(
                (const __attribute__((address_space(1))) unsigned int*)(src + c * 512),
                (__attribute__((address_space(3))) unsigned int*)&sA[buf][(wave * 2 + c) * 512],
                16, 0, 0);
    };

    // ---- prologue: stage iter 0 ----
    glds_a(0, 0);
    #pragma unroll
    for (int j = 0; j < 4; j++)
        xv[j] = *(const float4*)(x + (size_t)(s + bK + j) * NCOL + colb + bC);
    #pragma unroll
    for (int cc = 0; cc < 4; cc++) {
        int lc = bC + cc;
        bf16x4 w;
        #pragma unroll
        for (int j = 0; j < 4; j++)
            w[j] = (bf16)(((const float*)&xv[j])[cc]);
        *(bf16x4*)&sB[0][lc][bK ^ (((lc >> 2) & 3) << 3)] = w;
    }
    __syncthreads();   // drains the glds (vmcnt 0) + sB writes

    for (int it = 0; it < nIter; ++it) {
        const int cur = it & 1;
        const bool more = (it + 1) < nIter;

        // ---- issue next iter's loads (in flight during compute) ----
        if (more) {
            glds_a(1 - cur, it + 1);
            const int k0 = (it + 1) * BK;
            #pragma unroll
            for (int j = 0; j < 4; j++)
                xv[j] = *(const float4*)(x + (size_t)(s + k0 + bK + j) * NCOL + colb + bC);
        }

        // ---- compute from buf[cur] ----
        bf16x8 af[4], bfr[4];
        #pragma unroll
        for (int i = 0; i < 4; i++)
            af[i] = *(const bf16x8*)&sA[cur][((wave & 1) * 4 + i) * 512 + lane * 8];
        #pragma unroll
        for (int j = 0; j < 4; j++) {
            int lc = wc + j * 16 + lm;
            bfr[j] = *(const bf16x8*)&sB[cur][lc][kb ^ (((lc >> 2) & 3) << 3)];
        }
        #pragma unroll
        for (int i = 0; i < 4; i++)
            #pragma unroll
            for (int j = 0; j < 4; j++)
                acc[i][j] = __builtin_amdgcn_mfma_f32_16x16x32_bf16(af[i], bfr[j], acc[i][j], 0, 0, 0);

        // ---- stage next B tile, one barrier (drains glds + xv) ----
        if (more) {
            const int nxt = 1 - cur;
            #pragma unroll
            for (int cc = 0; cc < 4; cc++) {
                int lc = bC + cc;
                bf16x4 w;
                #pragma unroll
                for (int j = 0; j < 4; j++)
                    w[j] = (bf16)(((const float*)&xv[j])[cc]);
                *(bf16x4*)&sB[nxt][lc][bK ^ (((lc >> 2) & 3) << 3)] = w;
            }
            __syncthreads();
        }
    }

    // ---- epilogue: C/D layout col=lane&15, row=(lane>>4)*4+reg ----
    #pragma unroll
    for (int i = 0; i < 4; i++) {
        #pragma unroll
        for (int r = 0; r < 4; r++) {
            int row = row0 + wr + i * 16 + kq * 4 + r;
            if (row < g) {
                float* orow = out + (size_t)(s + row) * NCOL + colb + wc;
                #pragma unroll
                for (int j = 0; j < 4; j++)
                    orow[j * 16 + lm] = acc[i][j][r];
            }
        }
    }
}

// ---------------------------------------------------------------------------
// Fallback (round-0 kernel, verbatim): used if workspace is too small.
// ---------------------------------------------------------------------------
__global__ __launch_bounds__(256)
void matapply_fb(const float* __restrict__ x, MatPtrs mats, float* __restrict__ out)
{
    __shared__ bf16 sA[2][BM][BKp];
    __shared__ bf16 sB[2][BN][BKp];

    const int tid    = threadIdx.x;
    const int colb   = blockIdx.x * BN;
    const int tileid = blockIdx.y;

    const int grp  = c_tgrp[tileid];
    const int row0 = c_trow[tileid];
    const int g    = c_gsize[grp];
    const int s    = c_gstart[grp];
    const float* __restrict__ M = mats.p[grp];

    const int wave = tid >> 6;
    const int lane = tid & 63;
    const int wr   = (wave & 1) * 64;
    const int wc   = (wave >> 1) * 64;
    const int lm   = lane & 15;
    const int kq   = lane >> 4;
    const int kb   = kq * 8;

    const int aK = (tid & 7) * 4;
    const int aR = tid >> 3;
    const int bC = (tid & 31) * 4;
    const int bK = (tid >> 5) * 4;

    const int nIter = (g + BK - 1) / BK;

    f32x4 acc[4][4];
    #pragma unroll
    for (int i = 0; i < 4; i++)
        #pragma unroll
        for (int j = 0; j < 4; j++)
            acc[i][j] = (f32x4){0.f, 0.f, 0.f, 0.f};

    float4 av[4], xv[4];

    #pragma unroll
    for (int i = 0; i < 4; i++) {
        int r = aR + 32 * i;
        av[i] = make_float4(0.f, 0.f, 0.f, 0.f);
        if ((row0 + r) < g && aK < g)
            av[i] = *(const float4*)(M + (size_t)(row0 + r) * g + aK);
    }
    #pragma unroll
    for (int j = 0; j < 4; j++)
        xv[j] = *(const float4*)(x + (size_t)(s + bK + j) * NCOL + colb + bC);

    #pragma unroll
    for (int i = 0; i < 4; i++) {
        int r = aR + 32 * i;
        bf16x4 w;
        w[0] = (bf16)av[i].x; w[1] = (bf16)av[i].y; w[2] = (bf16)av[i].z; w[3] = (bf16)av[i].w;
        *(bf16x4*)&sA[0][r][aK] = w;
    }
    #pragma unroll
    for (int cc = 0; cc < 4; cc++) {
        int lc = bC + cc;
        bf16x4 w;
        #pragma unroll
        for (int j = 0; j < 4; j++)
            w[j] = (bf16)(((const float*)&xv[j])[cc]);
        *(bf16x4*)&sB[0][lc][bK ^ (((lc >> 2) & 3) << 3)] = w;
    }
    __syncthreads();

    for (int it = 0; it < nIter; ++it) {
        const int cur = it & 1;
        const bool more = (it + 1) < nIter;

        if (more) {
            const int k0 = (it + 1) * BK;
            #pragma unroll
            for (int i = 0; i < 4; i++) {
                int r = aR + 32 * i;
                av[i] = make_float4(0.f, 0.f, 0.f, 0.f);
                if ((row0 + r) < g && (k0 + aK) < g)
                    av[i] = *(const float4*)(M + (size_t)(row0 + r) * g + k0 + aK);
            }
            #pragma unroll
            for (int j = 0; j < 4; j++)
                xv[j] = *(const float4*)(x + (size_t)(s + k0 + bK + j) * NCOL + colb + bC);
        }

        bf16x8 af[4], bfr[4];
        #pragma unroll
        for (int i = 0; i < 4; i++)
            af[i] = *(const bf16x8*)&sA[cur][wr + i * 16 + lm][kb];
        #pragma unroll
        for (int j = 0; j < 4; j++) {
            int lc = wc + j * 16 + lm;
            bfr[j] = *(const bf16x8*)&sB[cur][lc][kb ^ (((lc >> 2) & 3) << 3)];
        }
        #pragma unroll
        for (int i = 0; i < 4; i++)
            #pragma unroll
            for (int j = 0; j < 4; j++)
                acc[i][j] = __builtin_amdgcn_mfma_f32_16x16x32_bf16(af[i], bfr[j], acc[i][j], 0, 0, 0);

        if (more) {
            const int nxt = 1 - cur;
            #pragma unroll
            for (int i = 0; i < 4; i++) {
                int r = aR + 32 * i;
                bf16x4 w;
                w[0] = (bf16)av[i].x; w[1] = (bf16)av[i].y; w[2] = (bf16)av[i].z; w[3] = (bf16)av[i].w;
                *(bf16x4*)&sA[nxt][r][aK] = w;
            }
            #pragma unroll
            for (int cc = 0; cc < 4; cc++) {
                int lc = bC + cc;
                bf16x4 w;
                #pragma unroll
                for (int j = 0; j < 4; j++)
                    w[j] = (bf16)(((const float*)&xv[j])[cc]);
                *(bf16x4*)&sB[nxt][lc][bK ^ (((lc >> 2) & 3) << 3)] = w;
            }
            __syncthreads();
        }
    }

    #pragma unroll
    for (int i = 0; i < 4; i++) {
        #pragma unroll
        for (int r = 0; r < 4; r++) {
            int row = row0 + wr + i * 16 + kq * 4 + r;
            if (row < g) {
                float* orow = out + (size_t)(s + row) * NCOL + colb + wc;
                #pragma unroll
                for (int j = 0; j < 4; j++)
                    orow[j * 16 + lm] = acc[i][j][r];
            }
        }
    }
}

extern "C" void kernel_launch(void* const* d_in, const int* in_sizes, int n_in,
                              void* d_out, int out_size, void* d_ws, size_t ws_size,
                              hipStream_t stream)
{
    const float* x = (const float*)d_in[0];
    MatPtrs mp;
    for (int i = 0; i < NG; i++) mp.p[i] = (const float*)d_in[1 + i];
    float* out = (float*)d_out;

    if (d_ws != nullptr && ws_size >= (size_t)WS_NEED) {
        prep_kernel<<<dim3(10, NTILES), dim3(256), 0, stream>>>(mp, (bf16*)d_ws);
        matapply_kernel<<<dim3(NCOL / BN, NTILES), dim3(256), 0, stream>>>(
            x, (const bf16*)d_ws, out);
    } else {
        matapply_fb<<<dim3(NCOL / BN, NTILES), dim3(256), 0, stream>>>(x, mp, out);
    }
}